// Round 10
// baseline (164.919 us; speedup 1.0000x reference)
//
#include <hip/hip_runtime.h>
#include <hip/hip_bf16.h>
#include <math.h>

#define BB 2
#define MM 8192
#define NN (BB * MM)
#define NBATCH (NN / 16)      // 1024 batches of 16 sorted points
#define NCELL 4096            // 16^3 morton cells per cloud
#define LOSS_BLOCKS 1024
#define PARTK_HALF 262144     // words per half: 256 qb * 1024

// ws layout (bytes):
#define PART_OFF   0          // 6 * LOSS_BLOCKS floats = 24576
#define RANK_OFF   24576      // NN ints = 65536
#define IDX_OFF    90112      // 2 MB: stage-1 partial keys; half0 region is
                              // overwritten with final out_idx by stage-2
#define PK_OFF     2187264    // NN float4 = 262144
#define SS_OFF     2449408    // NN floats = 65536
#define CELLID_OFF 2514944    // NN ints = 65536
#define CUR_OFF    2580480    // 2*NCELL ints = 32768
#define BBLO_OFF   2613248    // NBATCH uint4 = 16384
#define BBHI_OFF   2629632    // NBATCH uint4 = 16384

// order-preserving float<->uint transform (for atomicMin/Max bboxes)
__device__ __forceinline__ unsigned fenc(float f) {
    unsigned u = __float_as_uint(f);
    return (u & 0x80000000u) ? ~u : (u | 0x80000000u);
}
__device__ __forceinline__ float fdec(unsigned u) {
    return __uint_as_float((u & 0x80000000u) ? (u & 0x7FFFFFFFu) : ~u);
}

__device__ __forceinline__ unsigned mort3(unsigned x, unsigned y, unsigned z) {
    unsigned m = 0;
#pragma unroll
    for (int i = 0; i < 4; ++i) {
        m |= ((x >> i) & 1u) << (3 * i);
        m |= ((y >> i) & 1u) << (3 * i + 1);
        m |= ((z >> i) & 1u) << (3 * i + 2);
    }
    return m;
}

// Single block: LDS cell histogram + exclusive scan -> cursor; bbox init.
__global__ __launch_bounds__(1024) void countscan_kernel(const float* __restrict__ coords,
                                                         int* __restrict__ cellid,
                                                         int* __restrict__ cursor,
                                                         unsigned* __restrict__ bblo,
                                                         unsigned* __restrict__ bbhi) {
    __shared__ int scnt[2 * NCELL];   // 32 KB
    __shared__ int wsum[16];
    const int tid = threadIdx.x, lane = tid & 63, wv = tid >> 6;
#pragma unroll
    for (int j = 0; j < 8; ++j) scnt[tid + 1024 * j] = 0;
    __syncthreads();
#pragma unroll
    for (int j = 0; j < 16; ++j) {
        const int i = tid + 1024 * j;              // coalesced
        float x = coords[3 * i], y = coords[3 * i + 1], z = coords[3 * i + 2];
        int cx = min(15, max(0, (int)floorf(x) + 8));
        int cy = min(15, max(0, (int)floorf(y) + 8));
        int cz = min(15, max(0, (int)floorf(z) + 8));
        int cid = (i >> 13) * NCELL + (int)mort3((unsigned)cx, (unsigned)cy, (unsigned)cz);
        cellid[i] = cid;
        atomicAdd(&scnt[cid], 1);
    }
    __syncthreads();
    int v[8]; int run = 0;
#pragma unroll
    for (int i = 0; i < 8; ++i) { int t = scnt[tid * 8 + i]; v[i] = run; run += t; }
    int inc = run;
#pragma unroll
    for (int off = 1; off < 64; off <<= 1) {
        int y = __shfl_up(inc, off);
        if (lane >= off) inc += y;
    }
    int laneExcl = inc - run;
    if (lane == 63) wsum[wv] = inc;
    __syncthreads();
    int wbase = 0;
#pragma unroll
    for (int w = 0; w < 16; ++w) wbase += (w < wv) ? wsum[w] : 0;
    const int base = wbase + laneExcl;
#pragma unroll
    for (int i = 0; i < 8; ++i) cursor[tid * 8 + i] = base + v[i];
#pragma unroll
    for (int j = 0; j < 4; ++j) {
        bblo[tid * 4 + j] = 0xFFFFFFFFu;
        bbhi[tid * 4 + j] = 0u;
    }
}

// scatter into morton order + bbox maintenance via uint atomic min/max
__global__ void scatter_kernel(const float* __restrict__ coords, const float* __restrict__ scores,
                               const int* __restrict__ cellid, int* __restrict__ cursor,
                               float4* __restrict__ pk_s, float* __restrict__ s_s,
                               unsigned* __restrict__ bblo, unsigned* __restrict__ bbhi) {
    int i = blockIdx.x * 256 + threadIdx.x;
    if (i < NN) {
        int pos = atomicAdd(&cursor[cellid[i]], 1);
        float x = coords[3 * i], y = coords[3 * i + 1], z = coords[3 * i + 2];
        // MUST match dot ordering in knn so self-distance is exactly 0.
        float sq = fmaf(x, x, fmaf(y, y, z * z));
        pk_s[pos] = make_float4(x, y, z, sq);
        s_s[pos] = scores[i];
        const int b4 = (pos >> 4) * 4;
        atomicMin(&bblo[b4 + 0], fenc(x));
        atomicMin(&bblo[b4 + 1], fenc(y));
        atomicMin(&bblo[b4 + 2], fenc(z));
        atomicMax(&bbhi[b4 + 0], fenc(x));
        atomicMax(&bbhi[b4 + 1], fenc(y));
        atomicMax(&bbhi[b4 + 2], fenc(z));
    }
}

__device__ __forceinline__ void sort16(unsigned (&a)[16]) {
    // Batcher odd-even mergesort, ascending (verified R3-R9, absmax 0)
#pragma unroll
    for (int p2 = 1; p2 < 16; p2 <<= 1) {
#pragma unroll
        for (int k2 = p2; k2 >= 1; k2 >>= 1) {
#pragma unroll
            for (int j2 = k2 % p2; j2 + k2 < 16; j2 += 2 * k2) {
#pragma unroll
                for (int i2 = 0; i2 < k2; ++i2) {
                    if (i2 + j2 + k2 < 16) {
                        if (((i2 + j2) / (2 * p2)) == ((i2 + j2 + k2) / (2 * p2))) {
                            unsigned x = a[i2 + j2], y = a[i2 + j2 + k2];
                            a[i2 + j2]      = min(x, y);
                            a[i2 + j2 + k2] = max(x, y);
                        }
                    }
                }
            }
        }
    }
}

__device__ __forceinline__ void truncmerge(unsigned (&slot)[16], const unsigned (&kb)[16]) {
    // lowest-16 of (sorted slot ∪ sorted kb), result sorted (verified R3-R9)
    unsigned m[16];
#pragma unroll
    for (int k = 0; k < 16; ++k) m[k] = min(slot[k], kb[15 - k]);
#pragma unroll
    for (int st = 8; st >= 1; st >>= 1) {
#pragma unroll
        for (int i = 0; i < 16; ++i) {
            if ((i & st) == 0) {
                unsigned lo = min(m[i], m[i + st]);
                unsigned hi = max(m[i], m[i + st]);
                m[i] = lo; m[i + st] = hi;
            }
        }
    }
#pragma unroll
    for (int k = 0; k < 16; ++k) slot[k] = m[k];
}

// Stage 1: 512 blocks = (query-block qb, half h). Block scans half h's 256
// batches (16 per wave). Both halves compute the tight cooperative seed for
// the THRESHOLD; only the owner half keeps the seed keys (wave r). Exact:
// a point beating the global 16th-best has d2 < t_seed, so its batch passes
// the bbox prune, and it survives the half-local top-16. kmin-skip: if no
// lane's candidate beats its current 16th-best, the sort+merge is identity
// -> skipped. 64KB LDS -> 2 blocks/CU -> 8 waves/SIMD (2x R9's TLP).
__global__ __launch_bounds__(1024) void knn_part_kernel(const float4* __restrict__ pk_s,
                                                        const unsigned* __restrict__ bblo,
                                                        const unsigned* __restrict__ bbhi,
                                                        unsigned* __restrict__ partk) {
    __shared__ unsigned lds_k[16][16][64];  // [wave][slot][lane]: conflict-free
    const int tid = threadIdx.x, lane = tid & 63;
    const int wv = __builtin_amdgcn_readfirstlane(tid >> 6);
    const int qb = blockIdx.x >> 1;
    const int h  = blockIdx.x & 1;
    const int qbase = qb * 64;
    const int cloudbase = (qbase >> 13) << 13;
    const float4 p = pk_s[qbase + lane];
    const int sb0 = (qbase - cloudbase) >> 4;      // first local batch (mult of 4)
    const int r = sb0 & 15;
    const bool owner = (h == (sb0 >> 8));          // uniform
    const int seedb = (wv >= r && wv < r + 4) ? (sb0 + (wv - r)) : -1;  // uniform
    const int ownb = owner ? seedb : -1;
    const float4* __restrict__ pc = pk_s + cloudbase;
    const int bbase = cloudbase >> 4;

    unsigned slot[16];
#pragma unroll
    for (int k = 0; k < 16; ++k) slot[k] = 0x7F000000u + (unsigned)k;  // > any real key
    float t_f = 3.0e38f;

    auto batchU = [&](int bi, bool force) {
        unsigned kb[16];
#pragma unroll
        for (int i = 0; i < 16; ++i) {
            const int j = bi * 16 + i;             // uniform -> scalar loads
            const float4 c = pc[j];
            float dot = fmaf(p.x, c.x, fmaf(p.y, c.y, p.z * c.z));
            float d2  = fmaf(-2.0f, dot, p.w + c.w);   // exactly 0 for self
            kb[i] = (__float_as_uint(d2) & 0xFFFFE000u) | (unsigned)j;
        }
        unsigned kmin = kb[0];
#pragma unroll
        for (int i = 1; i < 16; ++i) kmin = min(kmin, kb[i]);
        if (force || __any(kmin < slot[15])) {     // skip identity merges
            sort16(kb);
            truncmerge(slot, kb);
            t_f = fminf(t_f, __uint_as_float((slot[15] & 0xFFFFE000u) + 0x2000u));
        }
    };

    // --- tight cooperative seed (both halves; threshold for all) ---
    if (seedb >= 0) batchU(seedb, true);
#pragma unroll
    for (int k = 0; k < 16; ++k) lds_k[wv][k][lane] = slot[k];
    __syncthreads();
    unsigned mg[16];
#pragma unroll
    for (int k = 0; k < 16; ++k) mg[k] = lds_k[r][k][lane];
#pragma unroll
    for (int w2 = 1; w2 < 4; ++w2) {
        unsigned ob[16];
#pragma unroll
        for (int k = 0; k < 16; ++k) ob[k] = lds_k[r + w2][k][lane];
        truncmerge(mg, ob);
    }
    __syncthreads();   // all lds_k reads done before later writes
    // owner half: wave r carries the merged seed keys; everyone else scans
    // fresh (non-owner outputs stay disjoint from owner outputs -> no dups)
    if (owner && wv == r) {
#pragma unroll
        for (int k = 0; k < 16; ++k) slot[k] = mg[k];
    } else {
#pragma unroll
        for (int k = 0; k < 16; ++k) slot[k] = 0x7F000000u + (unsigned)k;
    }
    t_f = __uint_as_float((mg[15] & 0xFFFFE000u) + 0x2000u);  // tight, tie-inclusive

    // --- bound scan over this half's 16 strided batches per wave ---
    const uint4* __restrict__ blo4 = (const uint4*)bblo;
    const uint4* __restrict__ bhi4 = (const uint4*)bbhi;
    const int hbase = h * 256;
    uint4 lo = blo4[bbase + hbase + wv];
    uint4 hi = bhi4[bbase + hbase + wv];
    for (int k2 = 0; k2 < 16; ++k2) {
        const int bi = hbase + wv + (k2 << 4);
        uint4 lo_n, hi_n;
        if (k2 + 1 < 16) {                         // uniform branch
            lo_n = blo4[bbase + bi + 16];
            hi_n = bhi4[bbase + bi + 16];
        }
        if (bi != ownb) {                          // uniform skip (seeded)
            float dx = fmaxf(fmaxf(fdec(lo.x) - p.x, p.x - fdec(hi.x)), 0.f);
            float dy = fmaxf(fmaxf(fdec(lo.y) - p.y, p.y - fdec(hi.y)), 0.f);
            float dz = fmaxf(fmaxf(fdec(lo.z) - p.z, p.z - fdec(hi.z)), 0.f);
            float lb = fmaf(dx, dx, fmaf(dy, dy, dz * dz));
            if (__any(fmaf(lb, 0.999f, -1e-5f) < t_f)) batchU(bi, false);
        }
        lo = lo_n; hi = hi_n;
    }

#pragma unroll
    for (int k = 0; k < 16; ++k) lds_k[wv][k][lane] = slot[k];

    // tree merge 16 -> 1 sorted lists (verified R3-R9)
    for (int half = 8; half >= 1; half >>= 1) {
        __syncthreads();
        if (wv < half) {
            unsigned a[16], m[16];
#pragma unroll
            for (int k = 0; k < 16; ++k) a[k] = lds_k[wv][k][lane];
#pragma unroll
            for (int k = 0; k < 16; ++k) m[k] = min(a[k], lds_k[wv + half][15 - k][lane]);
#pragma unroll
            for (int st = 8; st >= 1; st >>= 1) {
#pragma unroll
                for (int i = 0; i < 16; ++i) {
                    if ((i & st) == 0) {
                        unsigned lo2 = min(m[i], m[i + st]);
                        unsigned hi2 = max(m[i], m[i + st]);
                        m[i] = lo2; m[i + st] = hi2;
                    }
                }
            }
#pragma unroll
            for (int k = 0; k < 16; ++k) lds_k[wv][k][lane] = m[k];
        }
    }
    __syncthreads();
    if (wv == 0) {
#pragma unroll
        for (int k = 0; k < 16; ++k)
            partk[h * PARTK_HALF + qb * 1024 + k * 64 + lane] = lds_k[0][k][lane];
    }
}

// Stage 2: rank (verbatim R5/R9) + merge the two half-lists -> out_idx.
// out_idx overwrites partk's half-0 region: per-block read-then-write with a
// compiler+HW barrier (s_waitcnt vmcnt(0), memory clobber) between them.
__global__ __launch_bounds__(1024) void rankmerge_kernel(const float* __restrict__ s_s,
                                                         unsigned* __restrict__ partk,
                                                         int* __restrict__ out_rank) {
    __shared__ int lds_i[16][64];
    const int tid = threadIdx.x, lane = tid & 63;
    const int wv = __builtin_amdgcn_readfirstlane(tid >> 6);
    const int qbase = blockIdx.x * 64;
    const int cloudbase = (qbase >> 13) << 13;
    const float s = s_s[qbase + lane];
    const float* __restrict__ sc = s_s + cloudbase;
    int rank = 0;
    const int j0 = wv * 512;
    for (int jj = 0; jj < 512; jj += 16) {
#pragma unroll
        for (int i = 0; i < 16; ++i) {
            rank += (sc[j0 + jj + i] < s) ? 1 : 0;   // uniform -> scalar loads
        }
    }
    lds_i[wv][lane] = rank;
    __syncthreads();
    if (wv == 0) {
        int rsum = 0;
#pragma unroll
        for (int w = 0; w < 16; ++w) rsum += lds_i[w][lane];
        out_rank[qbase + lane] = rsum;

        unsigned a[16], b[16];
#pragma unroll
        for (int k = 0; k < 16; ++k) a[k] = partk[blockIdx.x * 1024 + k * 64 + lane];
#pragma unroll
        for (int k = 0; k < 16; ++k) b[k] = partk[PARTK_HALF + blockIdx.x * 1024 + k * 64 + lane];
        // all loads complete + compiler may not reorder the aliasing stores up
        __asm__ __volatile__("s_waitcnt vmcnt(0)" ::: "memory");
        truncmerge(a, b);
        int* out_idx = (int*)partk;
#pragma unroll
        for (int k = 0; k < 16; ++k)
            out_idx[(qbase + lane) * 16 + k] = (int)(a[k] & 0x1FFFu) + cloudbase;
    }
}

// one thread per (query,k) pair; block partials only (NO fences/atomics)
__global__ __launch_bounds__(256) void loss_kernel(const float* __restrict__ s_s,
                                                   const float4* __restrict__ pk_s,
                                                   const int* __restrict__ knn,
                                                   const int* __restrict__ rank,
                                                   float* __restrict__ partial) {
    __shared__ float red[4][6];
    const int t = blockIdx.x * 256 + threadIdx.x;
    const int q = t >> 4, k = t & 15;
    const int nb = knn[t];
    const float s  = s_s[q];
    const float sn = s_s[nb];
    const float diff = fabsf(s - sn);
    const float sim = 1.0f - diff;
    const float sg = 1.0f / (1.0f + expf(-2.0f * sim));

    float a_wd = 0.f, a_w = 0.f, a_pos = 0.f, a_neg = 0.f, snk = 0.f;
    if (k < 8) {
        float4 pq = pk_s[q];
        float4 pn = pk_s[nb];
        float dx = pq.x - pn.x, dy = pq.y - pn.y, dz = pq.z - pn.z;
        float d = sqrtf(dx * dx + dy * dy + dz * dz);
        float w = expf(-10.0f * d);
        a_wd = w * diff * diff;
        a_w  = w;
        a_pos = logf(sg + 1e-8f);
        snk = sn;
    } else {
        a_neg = logf(1.0f - sg + 1e-8f);
    }

    float nsum = snk;
#pragma unroll
    for (int off = 1; off < 16; off <<= 1) nsum += __shfl_xor(nsum, off);

    float a_sm = 0.f, a_di = 0.f;
    if (k == 0) {
        float t1 = s - nsum * 0.125f;
        a_sm = t1 * t1;
        float t2 = s - (float)rank[q] * (1.0f / 8191.0f);
        a_di = t2 * t2;
    }

#pragma unroll
    for (int off = 1; off < 64; off <<= 1) {
        a_wd  += __shfl_xor(a_wd, off);
        a_w   += __shfl_xor(a_w, off);
        a_pos += __shfl_xor(a_pos, off);
        a_neg += __shfl_xor(a_neg, off);
        a_sm  += __shfl_xor(a_sm, off);
        a_di  += __shfl_xor(a_di, off);
    }
    const int wv = threadIdx.x >> 6;
    if ((threadIdx.x & 63) == 0) {
        red[wv][0] = a_wd; red[wv][1] = a_w; red[wv][2] = a_pos;
        red[wv][3] = a_neg; red[wv][4] = a_sm; red[wv][5] = a_di;
    }
    __syncthreads();
    if (threadIdx.x < 6) {
        float v = red[0][threadIdx.x] + red[1][threadIdx.x] +
                  red[2][threadIdx.x] + red[3][threadIdx.x];
        partial[threadIdx.x * LOSS_BLOCKS + blockIdx.x] = v;
    }
}

__global__ __launch_bounds__(1024) void fin_kernel(const float* __restrict__ partial,
                                                   float* __restrict__ out) {
    __shared__ float red[16][6];
    const int tid = threadIdx.x;
    float a[6];
#pragma unroll
    for (int term = 0; term < 6; ++term) a[term] = partial[term * LOSS_BLOCKS + tid];
#pragma unroll
    for (int off = 1; off < 64; off <<= 1) {
#pragma unroll
        for (int term = 0; term < 6; ++term) a[term] += __shfl_xor(a[term], off);
    }
    if ((tid & 63) == 0) {
#pragma unroll
        for (int term = 0; term < 6; ++term) red[tid >> 6][term] = a[term];
    }
    __syncthreads();
    if (tid == 0) {
        float acc[6];
#pragma unroll
        for (int term = 0; term < 6; ++term) {
            float v = 0.f;
#pragma unroll
            for (int w = 0; w < 16; ++w) v += red[w][term];
            acc[term] = v;
        }
        float l_loc = acc[0] / fmaxf(acc[1], 1e-8f);
        float l_pos = -acc[2] / (float)(NN * 8);
        float l_neg = -acc[3] / (float)(NN * 8);
        float l_sm  = acc[4] / (float)NN;
        float l_di  = acc[5] / (float)NN;
        out[0] = l_loc + 0.5f * (l_pos + l_neg) + 0.3f * l_di + 0.2f * l_sm;
    }
}

extern "C" void kernel_launch(void* const* d_in, const int* in_sizes, int n_in,
                              void* d_out, int out_size, void* d_ws, size_t ws_size,
                              hipStream_t stream) {
    const float* scores = (const float*)d_in[0];
    const float* coords = (const float*)d_in[1];
    (void)in_sizes; (void)n_in; (void)out_size; (void)ws_size;

    char* ws = (char*)d_ws;
    float*    part  = (float*)(ws + PART_OFF);
    int*      rank  = (int*)(ws + RANK_OFF);
    unsigned* partk = (unsigned*)(ws + IDX_OFF);
    int*      knn   = (int*)(ws + IDX_OFF);      // stage-2 writes out_idx here
    float4*   pk_s  = (float4*)(ws + PK_OFF);
    float*    s_s   = (float*)(ws + SS_OFF);
    int*      cellid= (int*)(ws + CELLID_OFF);
    int*      cursor= (int*)(ws + CUR_OFF);
    unsigned* bblo  = (unsigned*)(ws + BBLO_OFF);
    unsigned* bbhi  = (unsigned*)(ws + BBHI_OFF);
    float*    out   = (float*)d_out;

    countscan_kernel<<<1, 1024, 0, stream>>>(coords, cellid, cursor, bblo, bbhi);
    scatter_kernel<<<64, 256, 0, stream>>>(coords, scores, cellid, cursor, pk_s, s_s, bblo, bbhi);
    knn_part_kernel<<<512, 1024, 0, stream>>>(pk_s, bblo, bbhi, partk);
    rankmerge_kernel<<<256, 1024, 0, stream>>>(s_s, partk, rank);
    loss_kernel<<<LOSS_BLOCKS, 256, 0, stream>>>(s_s, pk_s, knn, rank, part);
    fin_kernel<<<1, 1024, 0, stream>>>(part, out);
}